// Round 3
// baseline (148.622 us; speedup 1.0000x reference)
//
#include <hip/hip_runtime.h>

// Soft-DTW (gamma=0.1), normalized, batch 64, len 256, dim 8.
// W-space: W = -R/(gamma*ln2); recurrence W = Dw + m + log2(sum 2^(Wi-m)).
static constexpr float K1   = -14.426950408889634074f;   // -1/(gamma*ln2)
static constexpr float KOUT = -0.069314718055994530942f; // -gamma*ln2  (R = KOUT*W)
static constexpr float WBIG = -1.0e30f;                  // boundary (-inf surrogate)

// wave_shr:1 via DPP: lane l receives lane l-1's value; lane 0 keeps `fill`.
// VALU op — keeps the cross-lane move off the LDS/lgkmcnt path entirely.
__device__ __forceinline__ float dpp_shr1(float v, float fill) {
    int r = __builtin_amdgcn_update_dpp(__float_as_int(fill), __float_as_int(v),
                                        0x138 /*wave_shr:1*/, 0xf, 0xf, false);
    return __int_as_float(r);
}

__global__ void __launch_bounds__(64, 1)
sdtw_kernel(const float* __restrict__ x, const float* __restrict__ y,
            float* __restrict__ out)
{
    const int batch = blockIdx.x;
    const int pair  = blockIdx.y;   // 0: xy, 1: xx, 2: yy
    const int lane  = threadIdx.x;  // lane owns cols 4*lane..4*lane+3

    const float* A  = (pair == 2 ? y : x) + batch * 2048;  // rows side
    const float* Bp = (pair == 1 ? x : y) + batch * 2048;  // cols side

    __shared__ float xT[9][256];   // transposed rows: dims 0..7, [8] = |x_i|^2

    #pragma unroll
    for (int rr = 0; rr < 4; ++rr) {
        int r = lane + rr * 64;
        float4 a0 = *reinterpret_cast<const float4*>(A + r * 8);
        float4 a1 = *reinterpret_cast<const float4*>(A + r * 8 + 4);
        xT[0][r] = a0.x; xT[1][r] = a0.y; xT[2][r] = a0.z; xT[3][r] = a0.w;
        xT[4][r] = a1.x; xT[5][r] = a1.y; xT[6][r] = a1.z; xT[7][r] = a1.w;
        xT[8][r] = a0.x*a0.x + a0.y*a0.y + a0.z*a0.z + a0.w*a0.w
                 + a1.x*a1.x + a1.y*a1.y + a1.z*a1.z + a1.w*a1.w;
    }

    // col side: 4 columns x 8 dims in registers
    float b[4][8], nb[4];
    #pragma unroll
    for (int cc = 0; cc < 4; ++cc) {
        const float* bp = Bp + (4 * lane + cc) * 8;
        float4 b0 = *reinterpret_cast<const float4*>(bp);
        float4 b1 = *reinterpret_cast<const float4*>(bp + 4);
        b[cc][0]=b0.x; b[cc][1]=b0.y; b[cc][2]=b0.z; b[cc][3]=b0.w;
        b[cc][4]=b1.x; b[cc][5]=b1.y; b[cc][6]=b1.z; b[cc][7]=b1.w;
        nb[cc] = b0.x*b0.x + b0.y*b0.y + b0.z*b0.z + b0.w*b0.w
               + b1.x*b1.x + b1.y*b1.y + b1.z*b1.z + b1.w*b1.w;
    }

    __syncthreads();

    float up[4];
    up[0]=up[1]=up[2]=up[3] = WBIG;
    float own_last  = WBIG;
    float left_prev = (lane == 0) ? 0.0f : WBIG;  // lane0 s=0 upleft = R[-1][-1] = 0

    float xa[9], xb[9];
    #pragma unroll
    for (int d = 0; d < 9; ++d) xa[d] = xT[d][0];   // row 0 (only lane 0 uses it at s=0)

    auto step = [&](int s, float (&xc)[9], float (&xn)[9]) {
        // prefetch next row (off critical chain; waitcnt only guards next Dw)
        int ipf = s + 1 - lane;
        ipf = ipf < 0 ? 0 : (ipf > 255 ? 255 : ipf);
        #pragma unroll
        for (int d = 0; d < 9; ++d) xn[d] = xT[d][ipf];

        // cross-lane move: pure VALU, no DS
        float lin  = dpp_shr1(own_last, WBIG);  // lane l-1's last-col, step s-1
        float ulin = left_prev;                 // lane l-1's last-col, step s-2
        left_prev  = lin;

        const int i = s - lane;
        if (i >= 0 && i < 256) {
            float u0 = up[0], u1 = up[1], u2 = up[2], u3 = up[3];
            float ul0 = ulin;
            if (i == 0) {                        // row -1 boundary
                u0 = u1 = u2 = u3 = WBIG;
                if (lane != 0) ul0 = WBIG;
            }
            const float uu [4] = { u0, u1, u2, u3 };
            const float uls[4] = { ul0, u0, u1, u2 };

            // off-chain precompute: m2 = max(u,ul), p2 = exp2(u-m2)+exp2(ul-m2)
            float m2[4], p2[4];
            #pragma unroll
            for (int cc = 0; cc < 4; ++cc) {
                float d2 = uu[cc] - uls[cc];
                m2[cc] = fmaxf(uu[cc], uls[cc]);
                p2[cc] = 1.0f + __builtin_amdgcn_exp2f(fminf(d2, 0.0f - d2)); // 1+2^-|d|
            }

            // distances (independent FMAs, fully off-chain)
            float Dw[4];
            #pragma unroll
            for (int cc = 0; cc < 4; ++cc) {
                float acc = xc[0] * b[cc][0];
                #pragma unroll
                for (int d = 1; d < 8; ++d) acc = fmaf(xc[d], b[cc][d], acc);
                Dw[cc] = fmaf(-2.0f, acc, xc[8] + nb[cc]) * K1;
            }

            // serial chain: only `lft` is late per cell
            float lft = lin;
            #pragma unroll
            for (int cc = 0; cc < 4; ++cc) {
                float m   = fmaxf(m2[cc], lft);
                float ea  = __builtin_amdgcn_exp2f(lft - m);
                float eb  = __builtin_amdgcn_exp2f(m2[cc] - m);
                float sum = fmaf(p2[cc], eb, ea);
                float w   = (Dw[cc] + m) + __builtin_amdgcn_logf(sum); // logf = log2
                up[cc] = w;
                lft    = w;
            }
            own_last = lft;
        }
    };

    // 320 steps (even for the 2x unroll); step 319 is inert (i >= 256 for all lanes)
    for (int s = 0; s < 320; s += 2) {
        step(s,     xa, xb);
        step(s + 1, xb, xa);
    }

    if (lane == 63) {
        float r   = own_last * KOUT;                     // back to R-space
        float wgt = (pair == 0) ? (1.0f / 64.0f) : (-0.5f / 64.0f);
        atomicAdd(out, r * wgt);
    }
}

extern "C" void kernel_launch(void* const* d_in, const int* in_sizes, int n_in,
                              void* d_out, int out_size, void* d_ws, size_t ws_size,
                              hipStream_t stream)
{
    const float* x = (const float*)d_in[0];
    const float* y = (const float*)d_in[1];
    float* out = (float*)d_out;

    hipMemsetAsync(out, 0, out_size * sizeof(float), stream);
    hipLaunchKernelGGL(sdtw_kernel, dim3(64, 3), dim3(64), 0, stream, x, y, out);
}

// Round 4
// 126.015 us; speedup vs baseline: 1.1794x; 1.1794x over previous
//
#include <hip/hip_runtime.h>
#include <type_traits>

// Soft-DTW (gamma=0.1), normalized, batch 64, len 256, dim 8.
// W-space: W = -R/(gamma*ln2); recurrence W = Dw + logaddexp2(logaddexp2(u,ul), lft).
typedef _Float16 h2 __attribute__((ext_vector_type(2)));

static constexpr float K1   = -14.426950408889634074f;   // -1/(gamma*ln2)
static constexpr float M2K1 = 28.853900817779268148f;    // -2*K1
static constexpr float KOUT = -0.069314718055994530942f; // -gamma*ln2 (R = KOUT*W)
static constexpr float WBIG = -1.0e30f;                  // boundary (-inf surrogate)

// wave_shr:1 via DPP: lane l receives lane l-1's value; lane 0 keeps `fill`. Pure VALU.
__device__ __forceinline__ float dpp_shr1(float v, float fill) {
    int r = __builtin_amdgcn_update_dpp(__float_as_int(fill), __float_as_int(v),
                                        0x138 /*wave_shr:1*/, 0xf, 0xf, false);
    return __int_as_float(r);
}

__device__ __forceinline__ unsigned pack2(float a, float b) {
    h2 p; p[0] = (_Float16)a; p[1] = (_Float16)b;
    return __builtin_bit_cast(unsigned, p);
}

__device__ __forceinline__ float hdot(h2 a, h2 b, float c) {
#if __has_builtin(__builtin_amdgcn_fdot2)
    return __builtin_amdgcn_fdot2(a, b, c, false);
#else
    return fmaf((float)a[1], (float)b[1], fmaf((float)a[0], (float)b[0], c));
#endif
}

__global__ void __attribute__((amdgpu_waves_per_eu(1, 1))) __launch_bounds__(64, 1)
sdtw_kernel(const float* __restrict__ x, const float* __restrict__ y,
            float* __restrict__ out)
{
    const int batch = blockIdx.x;
    const int pair  = blockIdx.y;   // 0: xy, 1: xx, 2: yy
    const int lane  = threadIdx.x;  // lane owns cols 4*lane..4*lane+3

    const float* A  = (pair == 2 ? y : x) + batch * 2048;  // rows side
    const float* Bp = (pair == 1 ? x : y) + batch * 2048;  // cols side

    __shared__ unsigned xHs[4][256];  // f16x2-packed rows (dims 0-1,2-3,4-5,6-7)
    __shared__ float    nxs[256];     // |x_i|^2 from the CONVERTED values

    #pragma unroll
    for (int rr = 0; rr < 4; ++rr) {
        int r = lane + rr * 64;
        float4 a0 = *reinterpret_cast<const float4*>(A + r * 8);
        float4 a1 = *reinterpret_cast<const float4*>(A + r * 8 + 4);
        unsigned u0 = pack2(a0.x, a0.y), u1 = pack2(a0.z, a0.w);
        unsigned u2 = pack2(a1.x, a1.y), u3 = pack2(a1.z, a1.w);
        xHs[0][r] = u0; xHs[1][r] = u1; xHs[2][r] = u2; xHs[3][r] = u3;
        h2 h0 = __builtin_bit_cast(h2, u0), h1 = __builtin_bit_cast(h2, u1);
        h2 h2v = __builtin_bit_cast(h2, u2), h3 = __builtin_bit_cast(h2, u3);
        nxs[r] = hdot(h3, h3, hdot(h2v, h2v, hdot(h1, h1, hdot(h0, h0, 0.0f))));
    }

    // col side: 4 columns x 8 dims as f16x2 in registers (16 VGPRs)
    h2 bh[4][4]; float Knb[4];
    #pragma unroll
    for (int cc = 0; cc < 4; ++cc) {
        const float* bp = Bp + (4 * lane + cc) * 8;
        float4 b0 = *reinterpret_cast<const float4*>(bp);
        float4 b1 = *reinterpret_cast<const float4*>(bp + 4);
        bh[cc][0] = __builtin_bit_cast(h2, pack2(b0.x, b0.y));
        bh[cc][1] = __builtin_bit_cast(h2, pack2(b0.z, b0.w));
        bh[cc][2] = __builtin_bit_cast(h2, pack2(b1.x, b1.y));
        bh[cc][3] = __builtin_bit_cast(h2, pack2(b1.z, b1.w));
        float nb = hdot(bh[cc][3], bh[cc][3], hdot(bh[cc][2], bh[cc][2],
                   hdot(bh[cc][1], bh[cc][1], hdot(bh[cc][0], bh[cc][0], 0.0f))));
        Knb[cc] = K1 * nb;
    }

    __syncthreads();

    float up[4] = {WBIG, WBIG, WBIG, WBIG};   // W[i-1][4l+cc]
    float own_last  = WBIG;                   // W[i_prev][4l+3]
    float left_prev = (lane == 0) ? 0.0f : WBIG;  // lane0 s=0 upleft = R[-1][-1] = 0

    unsigned xc[4], xn[4]; float nxc, nxn;
    xc[0]=xHs[0][0]; xc[1]=xHs[1][0]; xc[2]=xHs[2][0]; xc[3]=xHs[3][0]; nxc=nxs[0];

    auto step = [&](auto phc, int s, unsigned (&XC)[4], float& NXC,
                    unsigned (&XN)[4], float& NXN) {
        constexpr int PH = decltype(phc)::value;  // 0=ramp-up, 1=steady, 2=ramp-down
        // prefetch next row (off critical chain)
        int ipf = s + 1 - lane;
        ipf = ipf < 0 ? 0 : (ipf > 255 ? 255 : ipf);
        XN[0]=xHs[0][ipf]; XN[1]=xHs[1][ipf]; XN[2]=xHs[2][ipf]; XN[3]=xHs[3][ipf];
        NXN = nxs[ipf];

        float lin  = dpp_shr1(own_last, WBIG);  // lane l-1 last-col, step s-1 -> left
        float ulin = left_prev;                 // lane l-1 last-col, step s-2 -> upleft
        left_prev  = lin;

        const int i = s - lane;
        bool act = (PH == 0) ? (i >= 0) : (PH == 2) ? (i < 256) : true;
        if (act) {
            float u0=up[0], u1=up[1], u2=up[2], u3=up[3];
            float ulc = ulin;
            if (PH == 0) {
                if (i == 0) { u0=u1=u2=u3=WBIG; if (lane) ulc = WBIG; }
            }
            const float uu [4] = {u0, u1, u2, u3};
            const float uls[4] = {ulc, u0, u1, u2};

            // distances via f16 dot2 (off-chain)
            float knx = K1 * NXC;
            float Dw[4], a2[4], Dwa2[4];
            h2 xv0 = __builtin_bit_cast(h2, XC[0]);
            h2 xv1 = __builtin_bit_cast(h2, XC[1]);
            h2 xv2 = __builtin_bit_cast(h2, XC[2]);
            h2 xv3 = __builtin_bit_cast(h2, XC[3]);
            #pragma unroll
            for (int cc = 0; cc < 4; ++cc) {
                float dot = hdot(xv3, bh[cc][3], hdot(xv2, bh[cc][2],
                            hdot(xv1, bh[cc][1], hdot(xv0, bh[cc][0], 0.0f))));
                Dw[cc] = fmaf(M2K1, dot, knx + Knb[cc]);
            }
            // off-chain pair reduce: a2 = logaddexp2(u, ul)
            #pragma unroll
            for (int cc = 0; cc < 4; ++cc) {
                float d2 = uu[cc] - uls[cc];
                float m2 = fmaxf(uu[cc], uls[cc]);
                float t  = __builtin_amdgcn_exp2f(-fabsf(d2));
                float a  = m2 + __builtin_amdgcn_logf(1.0f + t);
                a2[cc]   = a;
                Dwa2[cc] = Dw[cc] + a;
            }
            // serial chain: per cell sub -> exp2 -> add -> log2 -> add
            float lft = lin;
            #pragma unroll
            for (int cc = 0; cc < 4; ++cc) {
                float q   = Dw[cc] + lft;
                float dlt = a2[cc] - lft;
                float t2  = __builtin_amdgcn_exp2f(-fabsf(dlt));
                float l2  = __builtin_amdgcn_logf(1.0f + t2);
                float w   = fmaxf(Dwa2[cc], q) + l2;   // = Dw + logaddexp2(a2, lft)
                up[cc] = w;
                lft    = w;
            }
            own_last = lft;
        }
    };

    std::integral_constant<int,0> P0; std::integral_constant<int,1> P1;
    std::integral_constant<int,2> P2;
    for (int s = 0;   s < 64;  s += 2) { step(P0, s, xc, nxc, xn, nxn); step(P0, s+1, xn, nxn, xc, nxc); }
    for (int s = 64;  s < 256; s += 2) { step(P1, s, xc, nxc, xn, nxn); step(P1, s+1, xn, nxn, xc, nxc); }
    for (int s = 256; s < 320; s += 2) { step(P2, s, xc, nxc, xn, nxn); step(P2, s+1, xn, nxn, xc, nxc); }

    if (lane == 63) {
        float r   = own_last * KOUT;                     // back to R-space
        float wgt = (pair == 0) ? (1.0f / 64.0f) : (-0.5f / 64.0f);
        atomicAdd(out, r * wgt);
    }
}

extern "C" void kernel_launch(void* const* d_in, const int* in_sizes, int n_in,
                              void* d_out, int out_size, void* d_ws, size_t ws_size,
                              hipStream_t stream)
{
    const float* x = (const float*)d_in[0];
    const float* y = (const float*)d_in[1];
    float* out = (float*)d_out;

    hipMemsetAsync(out, 0, out_size * sizeof(float), stream);
    hipLaunchKernelGGL(sdtw_kernel, dim3(64, 3), dim3(64), 0, stream, x, y, out);
}